// Round 1
// baseline (680.929 us; speedup 1.0000x reference)
//
#include <hip/hip_runtime.h>
#include <math.h>

#define T_LEN 2048
#define NB 2
#define E_DIM 1024
#define F_DIM 1536
#define HQn 16
#define HKn 4
#define Dh 64
#define WIN 1024
#define GATE_CH 12

// ---------------------------------------------------------------------------
// NT GEMM: C[M][N] = A[M][K] * B[N][K]^T   (fp32, 128x64 block tile, 8x4 micro)
// ---------------------------------------------------------------------------
__global__ __launch_bounds__(256) void gemm_nt(
    const float* __restrict__ A, const float* __restrict__ B,
    float* __restrict__ C, int M, int N, int K)
{
  // LDS stored K-major (transposed) so microtile reads are ds_read_b128.
  // Stride 132/68: multiple of 4 floats (16B alignment) and 2-way-max banks.
  __shared__ __align__(16) float As[16][132];
  __shared__ __align__(16) float Bs[16][68];
  const int tid = threadIdx.x;
  const int ty = tid >> 4, tx = tid & 15;      // 16x16 threads
  const int row0 = blockIdx.x * 128;
  const int col0 = blockIdx.y * 64;

  float acc[8][4];
#pragma unroll
  for (int i = 0; i < 8; ++i)
#pragma unroll
    for (int j = 0; j < 4; ++j) acc[i][j] = 0.f;

  for (int k0 = 0; k0 < K; k0 += 16) {
    // stage A: 128 rows x 16 k = 512 float4, 2 per thread (transposed store)
#pragma unroll
    for (int p = 0; p < 2; ++p) {
      int idx = tid + p * 256;
      int r = idx >> 2, seg = idx & 3;
      float4 av = *(const float4*)(A + (size_t)(row0 + r) * K + k0 + seg * 4);
      As[seg*4+0][r] = av.x; As[seg*4+1][r] = av.y;
      As[seg*4+2][r] = av.z; As[seg*4+3][r] = av.w;
    }
    // stage B: 64 rows x 16 k = 256 float4, 1 per thread
    {
      int r = tid >> 2, seg = tid & 3;
      float4 bv = *(const float4*)(B + (size_t)(col0 + r) * K + k0 + seg * 4);
      Bs[seg*4+0][r] = bv.x; Bs[seg*4+1][r] = bv.y;
      Bs[seg*4+2][r] = bv.z; Bs[seg*4+3][r] = bv.w;
    }
    __syncthreads();
#pragma unroll
    for (int kk = 0; kk < 16; ++kk) {
      float4 a0 = *(const float4*)&As[kk][ty*8];
      float4 a1 = *(const float4*)&As[kk][ty*8+4];
      float4 b0 = *(const float4*)&Bs[kk][tx*4];
      float av[8] = {a0.x,a0.y,a0.z,a0.w,a1.x,a1.y,a1.z,a1.w};
      float bv[4] = {b0.x,b0.y,b0.z,b0.w};
#pragma unroll
      for (int i = 0; i < 8; ++i)
#pragma unroll
        for (int j = 0; j < 4; ++j) acc[i][j] += av[i]*bv[j];
    }
    __syncthreads();
  }
#pragma unroll
  for (int i = 0; i < 8; ++i) {
    float4 o = make_float4(acc[i][0],acc[i][1],acc[i][2],acc[i][3]);
    *(float4*)(C + (size_t)(row0 + ty*8 + i) * N + col0 + tx*4) = o;
  }
}

// ---------------------------------------------------------------------------
// Fused: gate = 3*sigmoid(x[:,:12]@wg^T); v += gate*ve; RoPE+RMS on q,k (inplace)
// qkv layout per token: [q(16*64) | k(4*64) | v(4*64)]
// ---------------------------------------------------------------------------
__global__ __launch_bounds__(256) void postproc(
    float* __restrict__ qkv, const float* __restrict__ x,
    const float* __restrict__ ve, const float* __restrict__ rcos,
    const float* __restrict__ rsin, const float* __restrict__ wg)
{
  const int token = blockIdx.x;          // b*T + t
  const int t = token & (T_LEN - 1);
  const int tid = threadIdx.x;
  __shared__ float gate[HKn];
  if (tid < HKn) {
    float g = 0.f;
#pragma unroll
    for (int c = 0; c < GATE_CH; ++c)
      g += x[(size_t)token * E_DIM + c] * wg[tid * GATE_CH + c];
    gate[tid] = 3.f / (1.f + __expf(-g));
  }
  const int wave = tid >> 6, lane = tid & 63;
  // RoPE + RMS for 16 q-heads + 4 k-heads (vectors 0..19), wave per vector
  for (int vi = wave; vi < HQn + HKn; vi += 4) {
    float* p = qkv + (size_t)token * F_DIM + vi * Dh;
    float y;
    if (lane < 32) {
      float x1 = p[lane], x2 = p[lane + 32];
      float c = rcos[t*32 + lane], s = rsin[t*32 + lane];
      y = x1 * c - x2 * s;
    } else {
      float x1 = p[lane - 32], x2 = p[lane];
      float c = rcos[t*32 + lane - 32], s = rsin[t*32 + lane - 32];
      y = x1 * s + x2 * c;
    }
    float ss = y * y;
#pragma unroll
    for (int o = 32; o; o >>= 1) ss += __shfl_xor(ss, o, 64);
    float scale = rsqrtf(ss * (1.f / Dh) + 1e-8f);
    p[lane] = y * scale;
  }
  __syncthreads();
  // v += gate * ve  (256 values per token, one per thread)
  {
    float g = gate[tid >> 6];
    size_t idx = (size_t)token * F_DIM + (HQn + HKn) * Dh + tid;
    qkv[idx] += g * ve[(size_t)token * (HKn * Dh) + tid];
  }
}

// ---------------------------------------------------------------------------
// Flash-style sliding-window attention. Block = (q-tile 64) x (head) x (batch).
// 256 threads, 16x16, 4x4 microtiles for both QK^T and PV. Online softmax.
// ---------------------------------------------------------------------------
__global__ __launch_bounds__(256) void attn_kernel(
    const float* __restrict__ qkv, float* __restrict__ att)
{
  const int qt = blockIdx.x;
  const int h  = blockIdx.y;
  const int b  = blockIdx.z;
  const int qb = qt * 64;
  const int hk = h >> 2;                 // GQA group = 4
  __shared__ __align__(16) float q_t[64][68];   // q transposed [d][q]
  __shared__ __align__(16) float kp [64][68];   // k transposed [d][j]; reused as P [j][q]
  __shared__ __align__(16) float vt [64][68];   // v [j][d]
  const int tid = threadIdx.x;
  const int ty = tid >> 4, tx = tid & 15;
  const float sc = 0.125f * 1.44269504088896f;  // 1/sqrt(64) * log2(e) folded into q

  const float* qbase = qkv + (size_t)(b*T_LEN + qb) * F_DIM + h * Dh;
#pragma unroll
  for (int p = 0; p < 4; ++p) {
    int idx = p*256 + tid;
    int r = idx >> 4, seg = idx & 15;
    float4 v = *(const float4*)(qbase + (size_t)r * F_DIM + seg * 4);
    q_t[seg*4+0][r] = v.x*sc; q_t[seg*4+1][r] = v.y*sc;
    q_t[seg*4+2][r] = v.z*sc; q_t[seg*4+3][r] = v.w*sc;
  }

  float m[4], l[4], Oa[4][4];
#pragma unroll
  for (int i = 0; i < 4; ++i) {
    m[i] = -1e30f; l[i] = 0.f;
#pragma unroll
    for (int j = 0; j < 4; ++j) Oa[i][j] = 0.f;
  }

  const int kt0 = (qt >= 16) ? qt - 16 : 0;
  const float* kbase = qkv + (size_t)(b*T_LEN) * F_DIM + HQn*Dh + hk*Dh;
  const float* vbase = qkv + (size_t)(b*T_LEN) * F_DIM + (HQn+HKn)*Dh + hk*Dh;

  for (int kt = kt0; kt <= qt; ++kt) {
    const int kb = kt * 64;
    __syncthreads();   // previous PV reads of kp/vt done
#pragma unroll
    for (int p = 0; p < 4; ++p) {
      int idx = p*256 + tid;
      int r = idx >> 4, seg = idx & 15;
      float4 kv = *(const float4*)(kbase + (size_t)(kb + r) * F_DIM + seg * 4);
      kp[seg*4+0][r] = kv.x; kp[seg*4+1][r] = kv.y;
      kp[seg*4+2][r] = kv.z; kp[seg*4+3][r] = kv.w;
      float4 vv = *(const float4*)(vbase + (size_t)(kb + r) * F_DIM + seg * 4);
      *(float4*)&vt[r][seg*4] = vv;
    }
    __syncthreads();

    float S[4][4];
#pragma unroll
    for (int i = 0; i < 4; ++i)
#pragma unroll
      for (int j = 0; j < 4; ++j) S[i][j] = 0.f;
#pragma unroll
    for (int d = 0; d < 64; ++d) {
      float4 qv = *(const float4*)&q_t[d][ty*4];
      float4 kv = *(const float4*)&kp[d][tx*4];
      float qa[4] = {qv.x,qv.y,qv.z,qv.w};
      float ka[4] = {kv.x,kv.y,kv.z,kv.w};
#pragma unroll
      for (int i = 0; i < 4; ++i)
#pragma unroll
        for (int j = 0; j < 4; ++j) S[i][j] += qa[i]*ka[j];
    }
    // mask only on edge tiles (interior tiles of the window are fully valid)
    if (kt == kt0 || kt == qt) {
#pragma unroll
      for (int i = 0; i < 4; ++i)
#pragma unroll
        for (int j = 0; j < 4; ++j) {
          int ig = qb + ty*4 + i, jg = kb + tx*4 + j;
          if (jg > ig || jg < ig - WIN) S[i][j] = -1e30f;
        }
    }
    // online softmax (rows owned by same ty across 16 tx lanes of one wave)
#pragma unroll
    for (int i = 0; i < 4; ++i) {
      float mx = fmaxf(fmaxf(S[i][0],S[i][1]), fmaxf(S[i][2],S[i][3]));
      mx = fmaxf(mx, __shfl_xor(mx, 1, 64));
      mx = fmaxf(mx, __shfl_xor(mx, 2, 64));
      mx = fmaxf(mx, __shfl_xor(mx, 4, 64));
      mx = fmaxf(mx, __shfl_xor(mx, 8, 64));
      float mn = fmaxf(m[i], mx);
      float al = exp2f(m[i] - mn);
      m[i] = mn;
      float rs = 0.f;
#pragma unroll
      for (int j = 0; j < 4; ++j) { S[i][j] = exp2f(S[i][j] - mn); rs += S[i][j]; }
      rs += __shfl_xor(rs, 1, 64);
      rs += __shfl_xor(rs, 2, 64);
      rs += __shfl_xor(rs, 4, 64);
      rs += __shfl_xor(rs, 8, 64);
      l[i] = l[i]*al + rs;
#pragma unroll
      for (int j = 0; j < 4; ++j) Oa[i][j] *= al;
    }
    __syncthreads();   // all QK reads of kp done; reuse as P
#pragma unroll
    for (int i = 0; i < 4; ++i)
#pragma unroll
      for (int j = 0; j < 4; ++j) kp[tx*4+j][ty*4+i] = S[i][j];
    __syncthreads();
    // PV: O[q][d] += P[q][j] * V[j][d]
#pragma unroll
    for (int jj = 0; jj < 64; ++jj) {
      float4 pv = *(const float4*)&kp[jj][ty*4];
      float4 vv = *(const float4*)&vt[jj][tx*4];
      float pa[4] = {pv.x,pv.y,pv.z,pv.w};
      float va[4] = {vv.x,vv.y,vv.z,vv.w};
#pragma unroll
      for (int i = 0; i < 4; ++i)
#pragma unroll
        for (int j = 0; j < 4; ++j) Oa[i][j] += pa[i]*va[j];
    }
  }
  float* obase = att + (size_t)(b*T_LEN + qb) * E_DIM + h * Dh;
#pragma unroll
  for (int i = 0; i < 4; ++i) {
    float inv = 1.f / l[i];
    float4 o = make_float4(Oa[i][0]*inv, Oa[i][1]*inv, Oa[i][2]*inv, Oa[i][3]*inv);
    *(float4*)(obase + (size_t)(ty*4 + i) * E_DIM + tx*4) = o;
  }
}

// ---------------------------------------------------------------------------
extern "C" void kernel_launch(void* const* d_in, const int* in_sizes, int n_in,
                              void* d_out, int out_size, void* d_ws, size_t ws_size,
                              hipStream_t stream)
{
  const float* x    = (const float*)d_in[0];
  const float* ve   = (const float*)d_in[1];
  const float* rc   = (const float*)d_in[2];
  const float* rs   = (const float*)d_in[3];
  const float* wqkv = (const float*)d_in[4];
  const float* wg   = (const float*)d_in[5];
  const float* wo   = (const float*)d_in[6];
  float* out = (float*)d_out;

  float* qkv = (float*)d_ws;                         // 4096*1536 fp32 = 25.2 MB
  float* att = qkv + (size_t)4096 * F_DIM;           // 4096*1024 fp32 = 16.8 MB

  // 1) QKV projection: [4096,1024] x [1536,1024]^T
  gemm_nt<<<dim3(4096/128, F_DIM/64), 256, 0, stream>>>(x, wqkv, qkv, 4096, F_DIM, E_DIM);
  // 2) gate + value-embed add + RoPE + RMS (in place on qkv)
  postproc<<<dim3(NB*T_LEN), 256, 0, stream>>>(qkv, x, ve, rc, rs, wg);
  // 3) sliding-window attention
  attn_kernel<<<dim3(T_LEN/64, HQn, NB), 256, 0, stream>>>(qkv, att);
  // 4) output projection: [4096,1024] x [1024,1024]^T
  gemm_nt<<<dim3(4096/128, E_DIM/64), 256, 0, stream>>>(att, wo, out, 4096, E_DIM, E_DIM);
}

// Round 3
// 225.200 us; speedup vs baseline: 3.0237x; 3.0237x over previous
//
#include <hip/hip_runtime.h>
#include <math.h>

#define T_LEN 2048
#define NB 2
#define E_DIM 1024
#define F_DIM 1536
#define HQn 16
#define HKn 4
#define Dh 64
#define WIN 1024
#define GATE_CH 12
#define PS 72   // LDS row stride (elems) for attention tiles: 144B, 16B-aligned

typedef unsigned short u16;
typedef __attribute__((ext_vector_type(8))) short bf16x8;
typedef __attribute__((ext_vector_type(4))) float f32x4;

__device__ __forceinline__ u16 f2bf(float f) {
  union { float f; unsigned int u; } v; v.f = f;
  unsigned int u = v.u + 0x7FFF + ((v.u >> 16) & 1);
  return (u16)(u >> 16);
}
__device__ __forceinline__ float bf2f(u16 h) {
  union { unsigned int u; float f; } v; v.u = ((unsigned int)h) << 16;
  return v.f;
}
__device__ __forceinline__ void async_copy16(const void* g, void* l) {
  __builtin_amdgcn_global_load_lds(
      (const __attribute__((address_space(1))) unsigned int*)g,
      (__attribute__((address_space(3))) unsigned int*)l, 16, 0, 0);
}

// ---------------------------------------------------------------------------
// fp32 -> bf16 conversion (RNE), 4 elems/thread
// ---------------------------------------------------------------------------
__global__ __launch_bounds__(256) void cvt_bf16(
    const float4* __restrict__ in, uint2* __restrict__ out, int n4)
{
  int i = blockIdx.x * 256 + threadIdx.x;
  if (i >= n4) return;
  float4 v = in[i];
  uint2 o;
  o.x = (unsigned)f2bf(v.x) | ((unsigned)f2bf(v.y) << 16);
  o.y = (unsigned)f2bf(v.z) | ((unsigned)f2bf(v.w) << 16);
  out[i] = o;
}

// ---------------------------------------------------------------------------
// bf16 MFMA GEMM (m97 structure): C[M][N] = A[M][K] * B[N][K]^T
// 128x128 tile, BK=32, 4 waves (2x2), 4x4 16x16x32 MFMA tiles per wave.
// STORE_BF16: 1 -> u16 C, 0 -> float C.
// ---------------------------------------------------------------------------
template<int STORE_BF16>
__global__ __launch_bounds__(256) void gemm_bf16(
    const u16* __restrict__ A, const u16* __restrict__ B,
    void* __restrict__ Cv, int M, int N, int K)
{
  __shared__ u16 As[128 * 32];
  __shared__ u16 Bs[128 * 32];
  const int tid = threadIdx.x;
  const int wave = tid >> 6, lane = tid & 63;
  const int quad = lane >> 4, lanelow = lane & 15;
  const int row0 = blockIdx.x * 128;
  const int col0 = blockIdx.y * 128;
  const int wm = (wave >> 1) * 64, wn = (wave & 1) * 64;

  f32x4 acc[4][4];
#pragma unroll
  for (int i = 0; i < 4; ++i)
#pragma unroll
    for (int j = 0; j < 4; ++j) acc[i][j] = (f32x4){0.f, 0.f, 0.f, 0.f};

  const int r1 = wave * 16 + (lane >> 2);       // staging row within tile
  const int c1 = (lane & 3) * 8;                // staging k-offset (elems)

  for (int k0 = 0; k0 < K; k0 += 32) {
    __syncthreads();
    // stage A rows r1, r1+64 and B rows r1, r1+64 (16B per lane each).
    // LDS dst per lane = wave-uniform base + lane*16B (required layout).
    async_copy16(A + (size_t)(row0 + r1) * K + k0 + c1,      &As[r1 * 32 + c1]);
    async_copy16(A + (size_t)(row0 + r1 + 64) * K + k0 + c1, &As[(r1 + 64) * 32 + c1]);
    async_copy16(B + (size_t)(col0 + r1) * K + k0 + c1,      &Bs[r1 * 32 + c1]);
    async_copy16(B + (size_t)(col0 + r1 + 64) * K + k0 + c1, &Bs[(r1 + 64) * 32 + c1]);
    __syncthreads();

    bf16x8 a[4], b[4];
#pragma unroll
    for (int i = 0; i < 4; ++i)
      a[i] = *(const bf16x8*)&As[(wm + i * 16 + lanelow) * 32 + quad * 8];
#pragma unroll
    for (int j = 0; j < 4; ++j)
      b[j] = *(const bf16x8*)&Bs[(wn + j * 16 + lanelow) * 32 + quad * 8];
#pragma unroll
    for (int i = 0; i < 4; ++i)
#pragma unroll
      for (int j = 0; j < 4; ++j)
        acc[i][j] = __builtin_amdgcn_mfma_f32_16x16x32_bf16(a[i], b[j], acc[i][j], 0, 0, 0);
  }

#pragma unroll
  for (int i = 0; i < 4; ++i)
#pragma unroll
    for (int j = 0; j < 4; ++j) {
      int r = row0 + wm + i * 16 + quad * 4;
      int c = col0 + wn + j * 16 + lanelow;
#pragma unroll
      for (int reg = 0; reg < 4; ++reg) {
        if (STORE_BF16)
          ((u16*)Cv)[(size_t)(r + reg) * N + c] = f2bf(acc[i][j][reg]);
        else
          ((float*)Cv)[(size_t)(r + reg) * N + c] = acc[i][j][reg];
      }
    }
}

// ---------------------------------------------------------------------------
// postproc: gate = 3*sigmoid(x[:,:12]@wg^T); RoPE+RMS on q,k; v += gate*ve.
// Reads bf16 qkv [tok][1536]; writes bf16 q_att [tok][16][64] (softmax scale
// * log2e folded in), k_att [tok][4][64], v_att [tok][4][64].
// ---------------------------------------------------------------------------
__global__ __launch_bounds__(256) void postproc_bf(
    const u16* __restrict__ qkv, const float* __restrict__ x,
    const float* __restrict__ ve, const float* __restrict__ rcos,
    const float* __restrict__ rsin, const float* __restrict__ wg,
    u16* __restrict__ qa, u16* __restrict__ ka, u16* __restrict__ va)
{
  const int token = blockIdx.x;
  const int t = token & (T_LEN - 1);
  const int tid = threadIdx.x;
  const int wave = tid >> 6, lane = tid & 63;
  __shared__ float gate[HKn];
  if (tid < HKn) {
    float g = 0.f;
#pragma unroll
    for (int c = 0; c < GATE_CH; ++c)
      g += x[(size_t)token * E_DIM + c] * wg[tid * GATE_CH + c];
    gate[tid] = 3.f / (1.f + __expf(-g));
  }
  __syncthreads();
  const int half = lane & 31;
  for (int vi = wave; vi < HQn + HKn; vi += 4) {
    const u16* p = qkv + (size_t)token * F_DIM + vi * Dh;
    float c = rcos[t * 32 + half], s = rsin[t * 32 + half];
    float x1 = bf2f(p[half]), x2 = bf2f(p[half + 32]);
    float y = (lane < 32) ? (x1 * c - x2 * s) : (x1 * s + x2 * c);
    float ss = y * y;
#pragma unroll
    for (int o = 32; o; o >>= 1) ss += __shfl_xor(ss, o, 64);
    float v = y * rsqrtf(ss * (1.f / Dh) + 1e-8f);
    if (vi < HQn)
      qa[((size_t)token * HQn + vi) * Dh + lane] = f2bf(v * 0.1803368801f); // 0.125*log2(e)
    else
      ka[((size_t)token * HKn + (vi - HQn)) * Dh + lane] = f2bf(v);
  }
  // v += gate * ve  (256 values per token)
  {
    float g = gate[tid >> 6];
    size_t vidx = (size_t)token * (HKn * Dh) + tid;
    va[vidx] = f2bf(bf2f(qkv[(size_t)token * F_DIM + (HQn + HKn) * Dh + tid]) + g * ve[vidx]);
  }
}

// ---------------------------------------------------------------------------
// MFMA flash attention, sliding window. Block = (q-tile 64, head, batch),
// 4 waves; wave w owns q rows w*16..w*16+15.
// S tile: Q[16x64] * K^T[64x64] via 4nt x 2k 16x16x32 MFMAs.
// P round-trips through LDS (C-layout -> A-layout) with an explicit barrier
// between write and read (do NOT rely on intra-wave DS ordering across the
// u16-store/short8-load type boundary — TBAA may reorder).
// ---------------------------------------------------------------------------
__global__ __launch_bounds__(256) void attn_mfma(
    const u16* __restrict__ qa, const u16* __restrict__ ka,
    const u16* __restrict__ va, u16* __restrict__ att)
{
  __shared__ u16 Qs[64 * PS];
  __shared__ u16 Ks[64 * PS];
  __shared__ u16 Vt[64 * PS];   // transposed: Vt[d][j]
  __shared__ u16 Pb[64 * PS];   // P in A-layout rows
  const int qt = blockIdx.x, h = blockIdx.y, b = blockIdx.z;
  const int hk = h >> 2;
  const int qb = qt * 64;
  const int tid = threadIdx.x;
  const int wave = tid >> 6, lane = tid & 63;
  const int quad = lane >> 4, lanelow = lane & 15;

  // stage Q (64 rows x 8 segs of 8 elems)
#pragma unroll
  for (int p = 0; p < 2; ++p) {
    int s = tid + p * 256;
    int r = s >> 3, seg = s & 7;
    *(uint4*)&Qs[r * PS + seg * 8] =
        *(const uint4*)(qa + ((size_t)(b * T_LEN + qb + r) * HQn + h) * Dh + seg * 8);
  }
  __syncthreads();
  bf16x8 aQ0 = *(const bf16x8*)&Qs[(wave * 16 + lanelow) * PS + quad * 8];
  bf16x8 aQ1 = *(const bf16x8*)&Qs[(wave * 16 + lanelow) * PS + 32 + quad * 8];

  f32x4 O[4];
  float m[4], l[4];
#pragma unroll
  for (int r = 0; r < 4; ++r) { m[r] = -1e30f; l[r] = 0.f; }
#pragma unroll
  for (int d = 0; d < 4; ++d) O[d] = (f32x4){0.f, 0.f, 0.f, 0.f};

  const int kt0 = (qt >= 16) ? qt - 16 : 0;
  for (int kt = kt0; kt <= qt; ++kt) {
    const int kb = kt * 64;
    __syncthreads();   // prior tile's LDS reads (Ks/Vt/Pb) done in all waves
    // stage K straight
#pragma unroll
    for (int p = 0; p < 2; ++p) {
      int s = tid + p * 256;
      int r = s >> 3, seg = s & 7;
      *(uint4*)&Ks[r * PS + seg * 8] =
          *(const uint4*)(ka + ((size_t)(b * T_LEN + kb + r) * HKn + hk) * Dh + seg * 8);
    }
    // stage V transposed: lane = j, wave handles segs 2w,2w+1
#pragma unroll
    for (int ssg = 0; ssg < 2; ++ssg) {
      int seg = wave * 2 + ssg;
      uint4 vv = *(const uint4*)(va + ((size_t)(b * T_LEN + kb + lane) * HKn + hk) * Dh + seg * 8);
      u16 tmp[8];
      *(uint4*)tmp = vv;
#pragma unroll
      for (int e = 0; e < 8; ++e) Vt[(seg * 8 + e) * PS + lane] = tmp[e];
    }
    __syncthreads();

    // S = Q K^T (scale already folded into Q, in log2 units)
    f32x4 S[4];
#pragma unroll
    for (int nt = 0; nt < 4; ++nt) {
      S[nt] = (f32x4){0.f, 0.f, 0.f, 0.f};
      bf16x8 b0 = *(const bf16x8*)&Ks[(nt * 16 + lanelow) * PS + quad * 8];
      bf16x8 b1 = *(const bf16x8*)&Ks[(nt * 16 + lanelow) * PS + 32 + quad * 8];
      S[nt] = __builtin_amdgcn_mfma_f32_16x16x32_bf16(aQ0, b0, S[nt], 0, 0, 0);
      S[nt] = __builtin_amdgcn_mfma_f32_16x16x32_bf16(aQ1, b1, S[nt], 0, 0, 0);
    }
    // mask edge tiles only
    if (kt == qt || kt == qt - 16) {
#pragma unroll
      for (int nt = 0; nt < 4; ++nt)
#pragma unroll
        for (int r = 0; r < 4; ++r) {
          int ig = qb + wave * 16 + quad * 4 + r;
          int jg = kb + nt * 16 + lanelow;
          if (jg > ig || jg < ig - WIN) S[nt][r] = -1e30f;
        }
    }
    // online softmax; row r held by 16 lanes sharing quad
#pragma unroll
    for (int r = 0; r < 4; ++r) {
      float mx = fmaxf(fmaxf(S[0][r], S[1][r]), fmaxf(S[2][r], S[3][r]));
      mx = fmaxf(mx, __shfl_xor(mx, 1, 64));
      mx = fmaxf(mx, __shfl_xor(mx, 2, 64));
      mx = fmaxf(mx, __shfl_xor(mx, 4, 64));
      mx = fmaxf(mx, __shfl_xor(mx, 8, 64));
      float mn = fmaxf(m[r], mx);
      float al = exp2f(m[r] - mn);
      m[r] = mn;
      float rs = 0.f;
#pragma unroll
      for (int nt = 0; nt < 4; ++nt) { S[nt][r] = exp2f(S[nt][r] - mn); rs += S[nt][r]; }
      rs += __shfl_xor(rs, 1, 64);
      rs += __shfl_xor(rs, 2, 64);
      rs += __shfl_xor(rs, 4, 64);
      rs += __shfl_xor(rs, 8, 64);
      l[r] = l[r] * al + rs;
#pragma unroll
      for (int d = 0; d < 4; ++d) O[d][r] *= al;
    }
    // P: C-layout regs -> LDS rows (own wave's 16 rows only)
#pragma unroll
    for (int nt = 0; nt < 4; ++nt)
#pragma unroll
      for (int r = 0; r < 4; ++r)
        Pb[(wave * 16 + quad * 4 + r) * PS + nt * 16 + lanelow] = f2bf(S[nt][r]);
    __syncthreads();   // P writes visible before A-fragment reads (fence)
    bf16x8 aP0 = *(const bf16x8*)&Pb[(wave * 16 + lanelow) * PS + quad * 8];
    bf16x8 aP1 = *(const bf16x8*)&Pb[(wave * 16 + lanelow) * PS + 32 + quad * 8];
#pragma unroll
    for (int dt = 0; dt < 4; ++dt) {
      bf16x8 b0 = *(const bf16x8*)&Vt[(dt * 16 + lanelow) * PS + quad * 8];
      bf16x8 b1 = *(const bf16x8*)&Vt[(dt * 16 + lanelow) * PS + 32 + quad * 8];
      O[dt] = __builtin_amdgcn_mfma_f32_16x16x32_bf16(aP0, b0, O[dt], 0, 0, 0);
      O[dt] = __builtin_amdgcn_mfma_f32_16x16x32_bf16(aP1, b1, O[dt], 0, 0, 0);
    }
  }
  // epilogue: O/l -> bf16 att [tok][h*64+d]
#pragma unroll
  for (int r = 0; r < 4; ++r) {
    float inv = 1.f / l[r];
    int row = qb + wave * 16 + quad * 4 + r;
#pragma unroll
    for (int dt = 0; dt < 4; ++dt)
      att[(size_t)(b * T_LEN + row) * E_DIM + h * Dh + dt * 16 + lanelow] =
          f2bf(O[dt][r] * inv);
  }
}

// ---------------------------------------------------------------------------
extern "C" void kernel_launch(void* const* d_in, const int* in_sizes, int n_in,
                              void* d_out, int out_size, void* d_ws, size_t ws_size,
                              hipStream_t stream)
{
  const float* x    = (const float*)d_in[0];
  const float* ve   = (const float*)d_in[1];
  const float* rc   = (const float*)d_in[2];
  const float* rs   = (const float*)d_in[3];
  const float* wqkv = (const float*)d_in[4];
  const float* wg   = (const float*)d_in[5];
  const float* wo   = (const float*)d_in[6];
  float* out = (float*)d_out;

  char* ws = (char*)d_ws;
  // ws layout (bytes); att reuses qkv_bf region (qkv_bf dead after postproc).
  u16* x_bf    = (u16*)(ws);                       //  8 MB  4096x1024
  u16* wqkv_bf = (u16*)(ws + 8388608);             //  3 MB  1536x1024
  u16* wo_bf   = (u16*)(ws + 11534336);            //  2 MB  1024x1024
  u16* qkv_bf  = (u16*)(ws + 13631488);            // 12 MB  4096x1536
  u16* att     = qkv_bf;                           //  8 MB  4096x1024 (reuse)
  u16* q_att   = (u16*)(ws + 26214400);            //  8 MB  4096x16x64
  u16* k_att   = (u16*)(ws + 34603008);            //  2 MB  4096x4x64
  u16* v_att   = (u16*)(ws + 36700160);            //  2 MB  4096x4x64

  // 1) fp32 -> bf16 conversions
  cvt_bf16<<<4096, 256, 0, stream>>>((const float4*)x,    (uint2*)x_bf,    1048576);
  cvt_bf16<<<1536, 256, 0, stream>>>((const float4*)wqkv, (uint2*)wqkv_bf,  393216);
  cvt_bf16<<<1024, 256, 0, stream>>>((const float4*)wo,   (uint2*)wo_bf,    262144);
  // 2) QKV projection (bf16 MFMA), bf16 out
  gemm_bf16<1><<<dim3(32, 12), 256, 0, stream>>>(x_bf, wqkv_bf, qkv_bf, 4096, F_DIM, E_DIM);
  // 3) gate + value-embed + RoPE + RMS -> packed bf16 q/k/v
  postproc_bf<<<NB * T_LEN, 256, 0, stream>>>(qkv_bf, x, ve, rc, rs, wg, q_att, k_att, v_att);
  // 4) MFMA flash attention -> bf16 att
  attn_mfma<<<dim3(T_LEN / 64, HQn, NB), 256, 0, stream>>>(q_att, k_att, v_att, att);
  // 5) output projection (bf16 MFMA), fp32 out
  gemm_bf16<0><<<dim3(32, 8), 256, 0, stream>>>(att, wo_bf, out, 4096, E_DIM, E_DIM);
}

// Round 4
// 201.971 us; speedup vs baseline: 3.3714x; 1.1150x over previous
//
#include <hip/hip_runtime.h>
#include <math.h>

#define T_LEN 2048
#define NB 2
#define E_DIM 1024
#define F_DIM 1536
#define HQn 16
#define HKn 4
#define Dh 64
#define WIN 1024
#define GATE_CH 12
#define PS 72   // LDS row stride (elems): 144B, 16B-aligned, bank-balanced for b128

typedef unsigned short u16;
typedef __attribute__((ext_vector_type(8))) short bf16x8;
typedef __attribute__((ext_vector_type(4))) float f32x4;

__device__ __forceinline__ u16 f2bf(float f) {
  union { float f; unsigned int u; } v; v.f = f;
  unsigned int u = v.u + 0x7FFF + ((v.u >> 16) & 1);
  return (u16)(u >> 16);
}
__device__ __forceinline__ float bf2f(u16 h) {
  union { unsigned int u; float f; } v; v.u = ((unsigned int)h) << 16;
  return v.f;
}
__device__ __forceinline__ void async_copy16(const void* g, void* l) {
  __builtin_amdgcn_global_load_lds(
      (const __attribute__((address_space(1))) unsigned int*)g,
      (__attribute__((address_space(3))) unsigned int*)l, 16, 0, 0);
}

// ---------------------------------------------------------------------------
// fp32 -> bf16 conversion (RNE), 4 elems/thread
// ---------------------------------------------------------------------------
__global__ __launch_bounds__(256) void cvt_bf16(
    const float4* __restrict__ in, uint2* __restrict__ out, int n4)
{
  int i = blockIdx.x * 256 + threadIdx.x;
  if (i >= n4) return;
  float4 v = in[i];
  uint2 o;
  o.x = (unsigned)f2bf(v.x) | ((unsigned)f2bf(v.y) << 16);
  o.y = (unsigned)f2bf(v.z) | ((unsigned)f2bf(v.w) << 16);
  out[i] = o;
}

// ---------------------------------------------------------------------------
// bf16 MFMA GEMM (m97 structure): C[M][N] = A[M][K] * B[N][K]^T
// 128x128 tile, BK=32, 4 waves (2x2), 4x4 16x16x32 MFMA tiles per wave.
// ---------------------------------------------------------------------------
template<int STORE_BF16>
__global__ __launch_bounds__(256) void gemm_bf16(
    const u16* __restrict__ A, const u16* __restrict__ B,
    void* __restrict__ Cv, int M, int N, int K)
{
  __shared__ u16 As[128 * 32];
  __shared__ u16 Bs[128 * 32];
  const int tid = threadIdx.x;
  const int wave = tid >> 6, lane = tid & 63;
  const int quad = lane >> 4, lanelow = lane & 15;
  const int row0 = blockIdx.x * 128;
  const int col0 = blockIdx.y * 128;
  const int wm = (wave >> 1) * 64, wn = (wave & 1) * 64;

  f32x4 acc[4][4];
#pragma unroll
  for (int i = 0; i < 4; ++i)
#pragma unroll
    for (int j = 0; j < 4; ++j) acc[i][j] = (f32x4){0.f, 0.f, 0.f, 0.f};

  const int r1 = wave * 16 + (lane >> 2);
  const int c1 = (lane & 3) * 8;

  for (int k0 = 0; k0 < K; k0 += 32) {
    __syncthreads();
    async_copy16(A + (size_t)(row0 + r1) * K + k0 + c1,      &As[r1 * 32 + c1]);
    async_copy16(A + (size_t)(row0 + r1 + 64) * K + k0 + c1, &As[(r1 + 64) * 32 + c1]);
    async_copy16(B + (size_t)(col0 + r1) * K + k0 + c1,      &Bs[r1 * 32 + c1]);
    async_copy16(B + (size_t)(col0 + r1 + 64) * K + k0 + c1, &Bs[(r1 + 64) * 32 + c1]);
    __syncthreads();

    bf16x8 a[4], b[4];
#pragma unroll
    for (int i = 0; i < 4; ++i)
      a[i] = *(const bf16x8*)&As[(wm + i * 16 + lanelow) * 32 + quad * 8];
#pragma unroll
    for (int j = 0; j < 4; ++j)
      b[j] = *(const bf16x8*)&Bs[(wn + j * 16 + lanelow) * 32 + quad * 8];
#pragma unroll
    for (int i = 0; i < 4; ++i)
#pragma unroll
      for (int j = 0; j < 4; ++j)
        acc[i][j] = __builtin_amdgcn_mfma_f32_16x16x32_bf16(a[i], b[j], acc[i][j], 0, 0, 0);
  }

#pragma unroll
  for (int i = 0; i < 4; ++i)
#pragma unroll
    for (int j = 0; j < 4; ++j) {
      int r = row0 + wm + i * 16 + quad * 4;
      int c = col0 + wn + j * 16 + lanelow;
#pragma unroll
      for (int reg = 0; reg < 4; ++reg) {
        if (STORE_BF16)
          ((u16*)Cv)[(size_t)(r + reg) * N + c] = f2bf(acc[i][j][reg]);
        else
          ((float*)Cv)[(size_t)(r + reg) * N + c] = acc[i][j][reg];
      }
    }
}

// ---------------------------------------------------------------------------
// postproc: gate = 3*sigmoid(x[:,:12]@wg^T); RoPE+RMS on q,k; v += gate*ve.
// ---------------------------------------------------------------------------
__global__ __launch_bounds__(256) void postproc_bf(
    const u16* __restrict__ qkv, const float* __restrict__ x,
    const float* __restrict__ ve, const float* __restrict__ rcos,
    const float* __restrict__ rsin, const float* __restrict__ wg,
    u16* __restrict__ qa, u16* __restrict__ ka, u16* __restrict__ va)
{
  const int token = blockIdx.x;
  const int t = token & (T_LEN - 1);
  const int tid = threadIdx.x;
  const int wave = tid >> 6, lane = tid & 63;
  __shared__ float gate[HKn];
  if (tid < HKn) {
    float g = 0.f;
#pragma unroll
    for (int c = 0; c < GATE_CH; ++c)
      g += x[(size_t)token * E_DIM + c] * wg[tid * GATE_CH + c];
    gate[tid] = 3.f / (1.f + __expf(-g));
  }
  __syncthreads();
  const int half = lane & 31;
  for (int vi = wave; vi < HQn + HKn; vi += 4) {
    const u16* p = qkv + (size_t)token * F_DIM + vi * Dh;
    float c = rcos[t * 32 + half], s = rsin[t * 32 + half];
    float x1 = bf2f(p[half]), x2 = bf2f(p[half + 32]);
    float y = (lane < 32) ? (x1 * c - x2 * s) : (x1 * s + x2 * c);
    float ss = y * y;
#pragma unroll
    for (int o = 32; o; o >>= 1) ss += __shfl_xor(ss, o, 64);
    float v = y * rsqrtf(ss * (1.f / Dh) + 1e-8f);
    if (vi < HQn)
      qa[((size_t)token * HQn + vi) * Dh + lane] = f2bf(v * 0.1803368801f); // 0.125*log2(e)
    else
      ka[((size_t)token * HKn + (vi - HQn)) * Dh + lane] = f2bf(v);
  }
  {
    float g = gate[tid >> 6];
    size_t vidx = (size_t)token * (HKn * Dh) + tid;
    va[vidx] = f2bf(bf2f(qkv[(size_t)token * F_DIM + (HQn + HKn) * Dh + tid]) + g * ve[vidx]);
  }
}

// ---------------------------------------------------------------------------
// V transpose: va[tok][hk][d] -> vt[(b*4+hk)*64 + d][t]  (t within batch)
// ---------------------------------------------------------------------------
__global__ __launch_bounds__(256) void transpose_v(
    const u16* __restrict__ va, u16* __restrict__ vt)
{
  __shared__ u16 tile[64][PS];
  const int bhk = blockIdx.y;             // b*4 + hk
  const int b = bhk >> 2, hk = bhk & 3;
  const int t0 = blockIdx.x * 64;
  const int tid = threadIdx.x;
#pragma unroll
  for (int p = 0; p < 2; ++p) {
    int s = tid + p * 256;
    int r = s >> 3, seg = s & 7;          // token r, d-segment
    *(uint4*)&tile[r][seg * 8] =
        *(const uint4*)(va + ((size_t)(b * T_LEN + t0 + r) * HKn + hk) * Dh + seg * 8);
  }
  __syncthreads();
#pragma unroll
  for (int p = 0; p < 2; ++p) {
    int s = tid + p * 256;
    int d = s >> 3, seg = s & 7;          // out row d, token-segment
    u16 tmp[8];
#pragma unroll
    for (int e = 0; e < 8; ++e) tmp[e] = tile[seg * 8 + e][d];
    *(uint4*)(vt + ((size_t)bhk * Dh + d) * T_LEN + t0 + seg * 8) = *(uint4*)tmp;
  }
}

// ---------------------------------------------------------------------------
// MFMA flash attention, sliding window, FIXED-SHIFT softmax.
// |S*scale*log2e| <= 11.54 (RMS-normed q,k) -> P = exp2(S-12) in [2^-23.5, 0.73]:
// no online max, no O rescale; l = lane-local partial sums, reduced once.
// Block = (q-tile 128, head, batch), 4 waves; wave owns 32 q rows.
// Pb overlays Qs (Q-frags read once at start). -12 folded into MFMA C-init.
// ---------------------------------------------------------------------------
__global__ __launch_bounds__(256) void attn_mfma(
    const u16* __restrict__ qa, const u16* __restrict__ ka,
    const u16* __restrict__ vt_g, u16* __restrict__ att)
{
  __shared__ u16 Qs[128 * PS];            // becomes Pb after Q-frag reads
  __shared__ u16 Ks[64 * PS];
  __shared__ u16 Vt[64 * PS];             // Vt[d][j]
  u16* Pb = Qs;
  const int qt = blockIdx.x, h = blockIdx.y, b = blockIdx.z;
  const int hk = h >> 2;
  const int qb = qt * 128;
  const int tid = threadIdx.x;
  const int wave = tid >> 6, lane = tid & 63;
  const int quad = lane >> 4, lanelow = lane & 15;

  // stage Q: 128 rows x 8 segs of 8 elems
#pragma unroll
  for (int p = 0; p < 4; ++p) {
    int s = tid + p * 256;
    int r = s >> 3, seg = s & 7;
    *(uint4*)&Qs[r * PS + seg * 8] =
        *(const uint4*)(qa + ((size_t)(b * T_LEN + qb + r) * HQn + h) * Dh + seg * 8);
  }
  __syncthreads();
  bf16x8 aQ[2][2];
#pragma unroll
  for (int hh = 0; hh < 2; ++hh)
#pragma unroll
    for (int kk = 0; kk < 2; ++kk)
      aQ[hh][kk] = *(const bf16x8*)&Qs[(wave * 32 + hh * 16 + lanelow) * PS + kk * 32 + quad * 8];

  f32x4 O[4][2];
  float l[2][4];
#pragma unroll
  for (int dt = 0; dt < 4; ++dt)
#pragma unroll
    for (int hh = 0; hh < 2; ++hh) O[dt][hh] = (f32x4){0.f, 0.f, 0.f, 0.f};
#pragma unroll
  for (int hh = 0; hh < 2; ++hh)
#pragma unroll
    for (int rr = 0; rr < 4; ++rr) l[hh][rr] = 0.f;

  const int i_lo = qb + wave * 32, i_hi = i_lo + 31;
  const int kt0 = (qt >= 8) ? qt * 2 - 16 : 0;
  const int kt1 = qt * 2 + 1;

  for (int kt = kt0; kt <= kt1; ++kt) {
    const int kb = kt * 64;
    __syncthreads();   // prior iter's Ks/Vt/Pb reads done (first iter: aQ reads done)
    // stage K (rows = k-tokens)
#pragma unroll
    for (int p = 0; p < 2; ++p) {
      int s = tid + p * 256;
      int r = s >> 3, seg = s & 7;
      *(uint4*)&Ks[r * PS + seg * 8] =
          *(const uint4*)(ka + ((size_t)(b * T_LEN + kb + r) * HKn + hk) * Dh + seg * 8);
    }
    // stage Vt from pre-transposed global (rows = d), coalesced b128
#pragma unroll
    for (int p = 0; p < 2; ++p) {
      int s = tid + p * 256;
      int r = s >> 3, seg = s & 7;
      *(uint4*)&Vt[r * PS + seg * 8] =
          *(const uint4*)(vt_g + ((size_t)(b * HKn + hk) * Dh + r) * T_LEN + kb + seg * 8);
    }
    __syncthreads();

    // wave-level skip: whole 32-row strip outside window for this tile
    const bool active = (kb <= i_hi) && (kb + 63 >= i_lo - WIN);
    if (active) {
      f32x4 S[4][2];
#pragma unroll
      for (int nt = 0; nt < 4; ++nt) {
        bf16x8 b0 = *(const bf16x8*)&Ks[(nt * 16 + lanelow) * PS + quad * 8];
        bf16x8 b1 = *(const bf16x8*)&Ks[(nt * 16 + lanelow) * PS + 32 + quad * 8];
#pragma unroll
        for (int hh = 0; hh < 2; ++hh) {
          f32x4 acc = (f32x4){-12.f, -12.f, -12.f, -12.f};   // fixed softmax shift
          acc = __builtin_amdgcn_mfma_f32_16x16x32_bf16(aQ[hh][0], b0, acc, 0, 0, 0);
          acc = __builtin_amdgcn_mfma_f32_16x16x32_bf16(aQ[hh][1], b1, acc, 0, 0, 0);
          S[nt][hh] = acc;
        }
      }
      const bool need_mask = (kb + 63 > i_lo) || (kb < i_hi - WIN);
      if (need_mask) {
#pragma unroll
        for (int nt = 0; nt < 4; ++nt)
#pragma unroll
          for (int hh = 0; hh < 2; ++hh)
#pragma unroll
            for (int rr = 0; rr < 4; ++rr) {
              int ig = i_lo + hh * 16 + quad * 4 + rr;
              int jg = kb + nt * 16 + lanelow;
              if (jg > ig || jg < ig - WIN) S[nt][hh][rr] = -1e30f;
            }
      }
      // P = exp2(S); lane-local row sums; pack to bf16; store to own Pb rows
#pragma unroll
      for (int hh = 0; hh < 2; ++hh)
#pragma unroll
        for (int rr = 0; rr < 4; ++rr) {
          float p0 = __builtin_amdgcn_exp2f(S[0][hh][rr]);
          float p1 = __builtin_amdgcn_exp2f(S[1][hh][rr]);
          float p2 = __builtin_amdgcn_exp2f(S[2][hh][rr]);
          float p3 = __builtin_amdgcn_exp2f(S[3][hh][rr]);
          l[hh][rr] += (p0 + p1) + (p2 + p3);
          int row = wave * 32 + hh * 16 + quad * 4 + rr;
          Pb[row * PS +  0 + lanelow] = f2bf(p0);
          Pb[row * PS + 16 + lanelow] = f2bf(p1);
          Pb[row * PS + 32 + lanelow] = f2bf(p2);
          Pb[row * PS + 48 + lanelow] = f2bf(p3);
        }
    }
    __syncthreads();   // P visible (and fence vs compiler reordering)
    if (active) {
      bf16x8 aP[2][2];
#pragma unroll
      for (int hh = 0; hh < 2; ++hh)
#pragma unroll
        for (int kk = 0; kk < 2; ++kk)
          aP[hh][kk] = *(const bf16x8*)&Pb[(wave * 32 + hh * 16 + lanelow) * PS + kk * 32 + quad * 8];
#pragma unroll
      for (int dt = 0; dt < 4; ++dt) {
        bf16x8 b0 = *(const bf16x8*)&Vt[(dt * 16 + lanelow) * PS + quad * 8];
        bf16x8 b1 = *(const bf16x8*)&Vt[(dt * 16 + lanelow) * PS + 32 + quad * 8];
#pragma unroll
        for (int hh = 0; hh < 2; ++hh) {
          O[dt][hh] = __builtin_amdgcn_mfma_f32_16x16x32_bf16(aP[hh][0], b0, O[dt][hh], 0, 0, 0);
          O[dt][hh] = __builtin_amdgcn_mfma_f32_16x16x32_bf16(aP[hh][1], b1, O[dt][hh], 0, 0, 0);
        }
      }
    }
  }
  // epilogue: reduce l across the 16 lanes sharing each row, divide, store
#pragma unroll
  for (int hh = 0; hh < 2; ++hh)
#pragma unroll
    for (int rr = 0; rr < 4; ++rr) {
      float s = l[hh][rr];
      s += __shfl_xor(s, 1, 64);
      s += __shfl_xor(s, 2, 64);
      s += __shfl_xor(s, 4, 64);
      s += __shfl_xor(s, 8, 64);
      float inv = 1.f / s;
      int row = qb + wave * 32 + hh * 16 + quad * 4 + rr;
#pragma unroll
      for (int dt = 0; dt < 4; ++dt)
        att[(size_t)(b * T_LEN + row) * E_DIM + h * Dh + dt * 16 + lanelow] =
            f2bf(O[dt][hh][rr] * inv);
    }
}

// ---------------------------------------------------------------------------
extern "C" void kernel_launch(void* const* d_in, const int* in_sizes, int n_in,
                              void* d_out, int out_size, void* d_ws, size_t ws_size,
                              hipStream_t stream)
{
  const float* x    = (const float*)d_in[0];
  const float* ve   = (const float*)d_in[1];
  const float* rc   = (const float*)d_in[2];
  const float* rs   = (const float*)d_in[3];
  const float* wqkv = (const float*)d_in[4];
  const float* wg   = (const float*)d_in[5];
  const float* wo   = (const float*)d_in[6];
  float* out = (float*)d_out;

  char* ws = (char*)d_ws;
  // ws layout; v_t reuses x_bf (dead after gemm1); att reuses qkv_bf (dead
  // after postproc). Strict stream ordering makes the overlaps safe.
  u16* x_bf    = (u16*)(ws);                       //  8 MB  4096x1024
  u16* v_t     = x_bf;                             //  2 MB  512x2048 (reuse)
  u16* wqkv_bf = (u16*)(ws + 8388608);             //  3 MB  1536x1024
  u16* wo_bf   = (u16*)(ws + 11534336);            //  2 MB  1024x1024
  u16* qkv_bf  = (u16*)(ws + 13631488);            // 12 MB  4096x1536
  u16* att     = qkv_bf;                           //  8 MB  4096x1024 (reuse)
  u16* q_att   = (u16*)(ws + 26214400);            //  8 MB  4096x16x64
  u16* k_att   = (u16*)(ws + 34603008);            //  2 MB  4096x4x64
  u16* v_att   = (u16*)(ws + 36700160);            //  2 MB  4096x4x64

  cvt_bf16<<<4096, 256, 0, stream>>>((const float4*)x,    (uint2*)x_bf,    1048576);
  cvt_bf16<<<1536, 256, 0, stream>>>((const float4*)wqkv, (uint2*)wqkv_bf,  393216);
  cvt_bf16<<<1024, 256, 0, stream>>>((const float4*)wo,   (uint2*)wo_bf,    262144);
  gemm_bf16<1><<<dim3(32, 12), 256, 0, stream>>>(x_bf, wqkv_bf, qkv_bf, 4096, F_DIM, E_DIM);
  postproc_bf<<<NB * T_LEN, 256, 0, stream>>>(qkv_bf, x, ve, rc, rs, wg, q_att, k_att, v_att);
  transpose_v<<<dim3(32, 8), 256, 0, stream>>>(v_att, v_t);
  attn_mfma<<<dim3(T_LEN / 128, HQn, NB), 256, 0, stream>>>(q_att, k_att, v_t, att);
  gemm_bf16<0><<<dim3(32, 8), 256, 0, stream>>>(att, wo_bf, out, 4096, E_DIM, E_DIM);
}

// Round 5
// 194.629 us; speedup vs baseline: 3.4986x; 1.0377x over previous
//
#include <hip/hip_runtime.h>
#include <math.h>

#define T_LEN 2048
#define NB 2
#define E_DIM 1024
#define F_DIM 1536
#define HQn 16
#define HKn 4
#define Dh 64
#define WIN 1024
#define GATE_CH 12
#define PS 72   // LDS row stride (elems): 144B, 16B-aligned

typedef unsigned short u16;
typedef __attribute__((ext_vector_type(8))) short bf16x8;
typedef __attribute__((ext_vector_type(4))) short bf16x4;
typedef __attribute__((ext_vector_type(4))) float f32x4;

// K=16 bf16 MFMA: probe builtin names; asm fallback (instr exists on gfx950).
#if __has_builtin(__builtin_amdgcn_mfma_f32_16x16x16bf16_1k)
#define MFMA16(A, B, C) __builtin_amdgcn_mfma_f32_16x16x16bf16_1k(A, B, C, 0, 0, 0)
#elif __has_builtin(__builtin_amdgcn_mfma_f32_16x16x16_bf16)
#define MFMA16(A, B, C) __builtin_amdgcn_mfma_f32_16x16x16_bf16(A, B, C, 0, 0, 0)
#else
static __device__ __forceinline__ f32x4 mfma16_asm(bf16x4 a, bf16x4 b, f32x4 c) {
  f32x4 d;
  asm volatile("s_nop 1\n\tv_mfma_f32_16x16x16_bf16 %0, %1, %2, %3\n\ts_nop 7\n\ts_nop 7"
               : "=v"(d) : "v"(a), "v"(b), "v"(c));
  return d;
}
#define MFMA16(A, B, C) mfma16_asm(A, B, C)
#endif

__device__ __forceinline__ u16 f2bf(float f) {
  union { float f; unsigned int u; } v; v.f = f;
  unsigned int u = v.u + 0x7FFF + ((v.u >> 16) & 1);
  return (u16)(u >> 16);
}
__device__ __forceinline__ float bf2f(u16 h) {
  union { unsigned int u; float f; } v; v.u = ((unsigned int)h) << 16;
  return v.f;
}
__device__ __forceinline__ void async_copy16(const void* g, void* l) {
  __builtin_amdgcn_global_load_lds(
      (const __attribute__((address_space(1))) unsigned int*)g,
      (__attribute__((address_space(3))) unsigned int*)l, 16, 0, 0);
}

// ---------------------------------------------------------------------------
// fp32 -> bf16 (RNE) for all three weight/input tensors in ONE launch.
// block ranges: [0,4096) x | [4096,5632) wqkv | [5632,6656) wo
// ---------------------------------------------------------------------------
__global__ __launch_bounds__(256) void cvt_all(
    const float4* __restrict__ x, const float4* __restrict__ wqkv,
    const float4* __restrict__ wo, uint2* __restrict__ xb,
    uint2* __restrict__ wqb, uint2* __restrict__ wob)
{
  int blk = blockIdx.x;
  const float4* in; uint2* out; int i;
  if (blk < 4096)       { in = x;    out = xb;  i = blk * 256 + threadIdx.x; }
  else if (blk < 5632)  { in = wqkv; out = wqb; i = (blk - 4096) * 256 + threadIdx.x; }
  else                  { in = wo;   out = wob; i = (blk - 5632) * 256 + threadIdx.x; }
  float4 v = in[i];
  uint2 o;
  o.x = (unsigned)f2bf(v.x) | ((unsigned)f2bf(v.y) << 16);
  o.y = (unsigned)f2bf(v.z) | ((unsigned)f2bf(v.w) << 16);
  out[i] = o;
}

// ---------------------------------------------------------------------------
// bf16 MFMA GEMM (m97 structure): C[M][N] = A[M][K] * B[N][K]^T
// ---------------------------------------------------------------------------
template<int STORE_BF16>
__global__ __launch_bounds__(256) void gemm_bf16(
    const u16* __restrict__ A, const u16* __restrict__ B,
    void* __restrict__ Cv, int M, int N, int K)
{
  __shared__ u16 As[128 * 32];
  __shared__ u16 Bs[128 * 32];
  const int tid = threadIdx.x;
  const int wave = tid >> 6, lane = tid & 63;
  const int quad = lane >> 4, lanelow = lane & 15;
  const int row0 = blockIdx.x * 128;
  const int col0 = blockIdx.y * 128;
  const int wm = (wave >> 1) * 64, wn = (wave & 1) * 64;

  f32x4 acc[4][4];
#pragma unroll
  for (int i = 0; i < 4; ++i)
#pragma unroll
    for (int j = 0; j < 4; ++j) acc[i][j] = (f32x4){0.f, 0.f, 0.f, 0.f};

  const int r1 = wave * 16 + (lane >> 2);
  const int c1 = (lane & 3) * 8;

  for (int k0 = 0; k0 < K; k0 += 32) {
    __syncthreads();
    async_copy16(A + (size_t)(row0 + r1) * K + k0 + c1,      &As[r1 * 32 + c1]);
    async_copy16(A + (size_t)(row0 + r1 + 64) * K + k0 + c1, &As[(r1 + 64) * 32 + c1]);
    async_copy16(B + (size_t)(col0 + r1) * K + k0 + c1,      &Bs[r1 * 32 + c1]);
    async_copy16(B + (size_t)(col0 + r1 + 64) * K + k0 + c1, &Bs[(r1 + 64) * 32 + c1]);
    __syncthreads();

    bf16x8 a[4], b[4];
#pragma unroll
    for (int i = 0; i < 4; ++i)
      a[i] = *(const bf16x8*)&As[(wm + i * 16 + lanelow) * 32 + quad * 8];
#pragma unroll
    for (int j = 0; j < 4; ++j)
      b[j] = *(const bf16x8*)&Bs[(wn + j * 16 + lanelow) * 32 + quad * 8];
#pragma unroll
    for (int i = 0; i < 4; ++i)
#pragma unroll
      for (int j = 0; j < 4; ++j)
        acc[i][j] = __builtin_amdgcn_mfma_f32_16x16x32_bf16(a[i], b[j], acc[i][j], 0, 0, 0);
  }

#pragma unroll
  for (int i = 0; i < 4; ++i)
#pragma unroll
    for (int j = 0; j < 4; ++j) {
      int r = row0 + wm + i * 16 + quad * 4;
      int c = col0 + wn + j * 16 + lanelow;
#pragma unroll
      for (int reg = 0; reg < 4; ++reg) {
        if (STORE_BF16)
          ((u16*)Cv)[(size_t)(r + reg) * N + c] = f2bf(acc[i][j][reg]);
        else
          ((float*)Cv)[(size_t)(r + reg) * N + c] = acc[i][j][reg];
      }
    }
}

// ---------------------------------------------------------------------------
// postproc: gate = 3*sigmoid(x[:,:12]@wg^T); RoPE+RMS on q,k; v += gate*ve.
// ---------------------------------------------------------------------------
__global__ __launch_bounds__(256) void postproc_bf(
    const u16* __restrict__ qkv, const float* __restrict__ x,
    const float* __restrict__ ve, const float* __restrict__ rcos,
    const float* __restrict__ rsin, const float* __restrict__ wg,
    u16* __restrict__ qa, u16* __restrict__ ka, u16* __restrict__ va)
{
  const int token = blockIdx.x;
  const int t = token & (T_LEN - 1);
  const int tid = threadIdx.x;
  const int wave = tid >> 6, lane = tid & 63;
  __shared__ float gate[HKn];
  if (tid < HKn) {
    float g = 0.f;
#pragma unroll
    for (int c = 0; c < GATE_CH; ++c)
      g += x[(size_t)token * E_DIM + c] * wg[tid * GATE_CH + c];
    gate[tid] = 3.f / (1.f + __expf(-g));
  }
  __syncthreads();
  const int half = lane & 31;
  for (int vi = wave; vi < HQn + HKn; vi += 4) {
    const u16* p = qkv + (size_t)token * F_DIM + vi * Dh;
    float c = rcos[t * 32 + half], s = rsin[t * 32 + half];
    float x1 = bf2f(p[half]), x2 = bf2f(p[half + 32]);
    float y = (lane < 32) ? (x1 * c - x2 * s) : (x1 * s + x2 * c);
    float ss = y * y;
#pragma unroll
    for (int o = 32; o; o >>= 1) ss += __shfl_xor(ss, o, 64);
    float v = y * rsqrtf(ss * (1.f / Dh) + 1e-8f);
    if (vi < HQn)
      qa[((size_t)token * HQn + vi) * Dh + lane] = f2bf(v * 0.1803368801f); // 0.125*log2(e)
    else
      ka[((size_t)token * HKn + (vi - HQn)) * Dh + lane] = f2bf(v);
  }
  {
    float g = gate[tid >> 6];
    size_t vidx = (size_t)token * (HKn * Dh) + tid;
    va[vidx] = f2bf(bf2f(qkv[(size_t)token * F_DIM + (HQn + HKn) * Dh + tid]) + g * ve[vidx]);
  }
}

// ---------------------------------------------------------------------------
// V transpose: va[tok][hk][d] -> vt[(b*4+hk)*64 + d][t]
// ---------------------------------------------------------------------------
__global__ __launch_bounds__(256) void transpose_v(
    const u16* __restrict__ va, u16* __restrict__ vt)
{
  __shared__ u16 tile[64][PS];
  const int bhk = blockIdx.y;
  const int b = bhk >> 2, hk = bhk & 3;
  const int t0 = blockIdx.x * 64;
  const int tid = threadIdx.x;
#pragma unroll
  for (int p = 0; p < 2; ++p) {
    int s = tid + p * 256;
    int r = s >> 3, seg = s & 7;
    *(uint4*)&tile[r][seg * 8] =
        *(const uint4*)(va + ((size_t)(b * T_LEN + t0 + r) * HKn + hk) * Dh + seg * 8);
  }
  __syncthreads();
#pragma unroll
  for (int p = 0; p < 2; ++p) {
    int s = tid + p * 256;
    int d = s >> 3, seg = s & 7;
    u16 tmp[8];
#pragma unroll
    for (int e = 0; e < 8; ++e) tmp[e] = tile[seg * 8 + e][d];
    *(uint4*)(vt + ((size_t)bhk * Dh + d) * T_LEN + t0 + seg * 8) = *(uint4*)tmp;
  }
}

// ---------------------------------------------------------------------------
// MFMA flash attention v3: S^T formulation, fixed-shift softmax, register P.
//  - S^T = K·Q^T (A=K,B=Q) -> C-layout lane holds P^T at q=lane&15, j=quad*4+reg
//    == B-operand layout of K=16 MFMA, so PV (O^T = V^T·P^T) feeds P straight
//    from registers: NO LDS round-trip, NO mid-iteration barrier.
//  - K/V LDS double-buffered with register prefetch: ONE barrier per iter.
//  - Q fragments loaded directly from global (no Q LDS).
//  - |S|<=11.54 (RMS-normed q,k): P=exp2(S-12), no online max, l summed once.
// Block = (q-tile 128, head, batch), 4 waves * 32 q rows.
// ---------------------------------------------------------------------------
__global__ __launch_bounds__(256) void attn_mfma(
    const u16* __restrict__ qa, const u16* __restrict__ ka,
    const u16* __restrict__ vt_g, u16* __restrict__ att)
{
  __shared__ u16 Ks[2][64 * PS];   // [buf][j][d]
  __shared__ u16 Vt[2][64 * PS];   // [buf][d][j]
  const int qt = blockIdx.x, h = blockIdx.y, b = blockIdx.z;
  const int hk = h >> 2;
  const int qb = qt * 128;
  const int tid = threadIdx.x;
  const int wave = tid >> 6, lane = tid & 63;
  const int quad = lane >> 4, lanelow = lane & 15;

  // Q fragments (B-operand: n=q=lanelow, k=d=quad*8+j) direct from global
  bf16x8 aQ[2][2];
#pragma unroll
  for (int hh = 0; hh < 2; ++hh)
#pragma unroll
    for (int kk = 0; kk < 2; ++kk)
      aQ[hh][kk] = *(const bf16x8*)(qa +
          ((size_t)(b * T_LEN + qb + wave * 32 + hh * 16 + lanelow) * HQn + h) * Dh +
          kk * 32 + quad * 8);

  f32x4 O[4][2];                   // [dt][hh], O^T C-layout (col=q, row=d_local)
  float l[2] = {0.f, 0.f};
#pragma unroll
  for (int dt = 0; dt < 4; ++dt)
#pragma unroll
    for (int hh = 0; hh < 2; ++hh) O[dt][hh] = (f32x4){0.f, 0.f, 0.f, 0.f};

  const int i_lo = qb + wave * 32, i_hi = i_lo + 31;
  const int kt0 = (qt >= 8) ? qt * 2 - 16 : 0;
  const int kt1 = qt * 2 + 1;

  // staging coords: 512 slots = 64 rows x 8 segs of 8 elems; 2 per thread
  const int sr0 = tid >> 3,           sc0 = (tid & 7) * 8;
  const int sr1 = (tid + 256) >> 3,   sc1 = ((tid + 256) & 7) * 8;
  const u16* kg = ka + (size_t)(b * T_LEN) * (HKn * Dh) + hk * Dh;
  const u16* vg = vt_g + (size_t)(b * HKn + hk) * Dh * T_LEN;

  // prologue: stage tile kt0 into buf 0
  {
    const int kb = kt0 * 64;
    uint4 k0 = *(const uint4*)(kg + (size_t)(kb + sr0) * (HKn * Dh) + sc0);
    uint4 k1 = *(const uint4*)(kg + (size_t)(kb + sr1) * (HKn * Dh) + sc1);
    uint4 v0 = *(const uint4*)(vg + (size_t)sr0 * T_LEN + kb + sc0);
    uint4 v1 = *(const uint4*)(vg + (size_t)sr1 * T_LEN + kb + sc1);
    *(uint4*)&Ks[0][sr0 * PS + sc0] = k0;
    *(uint4*)&Ks[0][sr1 * PS + sc1] = k1;
    *(uint4*)&Vt[0][sr0 * PS + sc0] = v0;
    *(uint4*)&Vt[0][sr1 * PS + sc1] = v1;
  }

  for (int kt = kt0; kt <= kt1; ++kt) {
    const int buf = (kt - kt0) & 1;
    const int kb = kt * 64;
    // issue prefetch for kt+1 (in flight during compute)
    uint4 k0, k1, v0, v1;
    const bool more = (kt < kt1);
    if (more) {
      const int nb = kb + 64;
      k0 = *(const uint4*)(kg + (size_t)(nb + sr0) * (HKn * Dh) + sc0);
      k1 = *(const uint4*)(kg + (size_t)(nb + sr1) * (HKn * Dh) + sc1);
      v0 = *(const uint4*)(vg + (size_t)sr0 * T_LEN + nb + sc0);
      v1 = *(const uint4*)(vg + (size_t)sr1 * T_LEN + nb + sc1);
    }
    __syncthreads();   // LDS[buf] writes from previous iter visible

    const bool active = (kb <= i_hi) && (kb + 63 >= i_lo - WIN);
    if (active) {
      // S^T: A = K-frag (m=j), B = Q-frag (n=q); -12 fixed shift in C-init
      f32x4 St[4][2];
#pragma unroll
      for (int jt = 0; jt < 4; ++jt) {
        bf16x8 aK0 = *(const bf16x8*)&Ks[buf][(jt * 16 + lanelow) * PS + quad * 8];
        bf16x8 aK1 = *(const bf16x8*)&Ks[buf][(jt * 16 + lanelow) * PS + 32 + quad * 8];
#pragma unroll
        for (int hh = 0; hh < 2; ++hh) {
          f32x4 acc = (f32x4){-12.f, -12.f, -12.f, -12.f};
          acc = __builtin_amdgcn_mfma_f32_16x16x32_bf16(aK0, aQ[hh][0], acc, 0, 0, 0);
          acc = __builtin_amdgcn_mfma_f32_16x16x32_bf16(aK1, aQ[hh][1], acc, 0, 0, 0);
          St[jt][hh] = acc;
        }
      }
      const bool need_mask = (kb + 63 > i_lo) || (kb < i_hi - WIN);
      if (need_mask) {
#pragma unroll
        for (int jt = 0; jt < 4; ++jt)
#pragma unroll
          for (int hh = 0; hh < 2; ++hh)
#pragma unroll
            for (int rr = 0; rr < 4; ++rr) {
              int ig = i_lo + hh * 16 + lanelow;          // query (col)
              int jg = kb + jt * 16 + quad * 4 + rr;      // key (row)
              if (jg > ig || jg < ig - WIN) St[jt][hh][rr] = -1e30f;
            }
      }
      // P = exp2(S^T); lane-local l partials (q fixed = lanelow); pack to regs
      bf16x4 Pt[4][2];
#pragma unroll
      for (int jt = 0; jt < 4; ++jt)
#pragma unroll
        for (int hh = 0; hh < 2; ++hh) {
          float p0 = __builtin_amdgcn_exp2f(St[jt][hh][0]);
          float p1 = __builtin_amdgcn_exp2f(St[jt][hh][1]);
          float p2 = __builtin_amdgcn_exp2f(St[jt][hh][2]);
          float p3 = __builtin_amdgcn_exp2f(St[jt][hh][3]);
          l[hh] += (p0 + p1) + (p2 + p3);
          bf16x4 pk;
          pk[0] = (short)f2bf(p0); pk[1] = (short)f2bf(p1);
          pk[2] = (short)f2bf(p2); pk[3] = (short)f2bf(p3);
          Pt[jt][hh] = pk;
        }
      // PV: O^T[d][q] += V^T-frag (A: m=d, k=j=quad*4+jj) * P^T (B from regs)
#pragma unroll
      for (int dt = 0; dt < 4; ++dt)
#pragma unroll
        for (int jt = 0; jt < 4; ++jt) {
          bf16x4 aV = *(const bf16x4*)&Vt[buf][(dt * 16 + lanelow) * PS + jt * 16 + quad * 4];
#pragma unroll
          for (int hh = 0; hh < 2; ++hh)
            O[dt][hh] = MFMA16(aV, Pt[jt][hh], O[dt][hh]);
        }
    }
    // write prefetched tile into the other buffer (before next barrier)
    if (more) {
      const int nbuf = buf ^ 1;
      *(uint4*)&Ks[nbuf][sr0 * PS + sc0] = k0;
      *(uint4*)&Ks[nbuf][sr1 * PS + sc1] = k1;
      *(uint4*)&Vt[nbuf][sr0 * PS + sc0] = v0;
      *(uint4*)&Vt[nbuf][sr1 * PS + sc1] = v1;
    }
  }

  // epilogue: reduce l across quads (q = lanelow fixed per lane), store O^T/l
#pragma unroll
  for (int hh = 0; hh < 2; ++hh) {
    float s = l[hh];
    s += __shfl_xor(s, 16, 64);
    s += __shfl_xor(s, 32, 64);
    float inv = 1.f / s;
    int qg = qb + wave * 32 + hh * 16 + lanelow;
    u16* obase = att + (size_t)(b * T_LEN + qg) * E_DIM + h * Dh;
#pragma unroll
    for (int dt = 0; dt < 4; ++dt) {
      bf16x4 ov;
      ov[0] = (short)f2bf(O[dt][hh][0] * inv);
      ov[1] = (short)f2bf(O[dt][hh][1] * inv);
      ov[2] = (short)f2bf(O[dt][hh][2] * inv);
      ov[3] = (short)f2bf(O[dt][hh][3] * inv);
      *(bf16x4*)(obase + dt * 16 + quad * 4) = ov;   // 8B store, d consecutive
    }
  }
}

// ---------------------------------------------------------------------------
extern "C" void kernel_launch(void* const* d_in, const int* in_sizes, int n_in,
                              void* d_out, int out_size, void* d_ws, size_t ws_size,
                              hipStream_t stream)
{
  const float* x    = (const float*)d_in[0];
  const float* ve   = (const float*)d_in[1];
  const float* rc   = (const float*)d_in[2];
  const float* rs   = (const float*)d_in[3];
  const float* wqkv = (const float*)d_in[4];
  const float* wg   = (const float*)d_in[5];
  const float* wo   = (const float*)d_in[6];
  float* out = (float*)d_out;

  char* ws = (char*)d_ws;
  u16* x_bf    = (u16*)(ws);                       //  8 MB  4096x1024
  u16* v_t     = x_bf;                             //  2 MB  512x2048 (reuse, x_bf dead after gemm1)
  u16* wqkv_bf = (u16*)(ws + 8388608);             //  3 MB  1536x1024
  u16* wo_bf   = (u16*)(ws + 11534336);            //  2 MB  1024x1024
  u16* qkv_bf  = (u16*)(ws + 13631488);            // 12 MB  4096x1536
  u16* att     = qkv_bf;                           //  8 MB  (reuse, qkv dead after postproc)
  u16* q_att   = (u16*)(ws + 26214400);            //  8 MB  4096x16x64
  u16* k_att   = (u16*)(ws + 34603008);            //  2 MB  4096x4x64
  u16* v_att   = (u16*)(ws + 36700160);            //  2 MB  4096x4x64

  cvt_all<<<6656, 256, 0, stream>>>((const float4*)x, (const float4*)wqkv,
                                    (const float4*)wo, (uint2*)x_bf,
                                    (uint2*)wqkv_bf, (uint2*)wo_bf);
  gemm_bf16<1><<<dim3(32, 12), 256, 0, stream>>>(x_bf, wqkv_bf, qkv_bf, 4096, F_DIM, E_DIM);
  postproc_bf<<<NB * T_LEN, 256, 0, stream>>>(qkv_bf, x, ve, rc, rs, wg, q_att, k_att, v_att);
  transpose_v<<<dim3(32, 8), 256, 0, stream>>>(v_att, v_t);
  attn_mfma<<<dim3(T_LEN / 128, HQn, NB), 256, 0, stream>>>(q_att, k_att, v_t, att);
  gemm_bf16<0><<<dim3(32, 8), 256, 0, stream>>>(att, wo_bf, out, 4096, E_DIM, E_DIM);
}

// Round 6
// 181.572 us; speedup vs baseline: 3.7502x; 1.0719x over previous
//
#include <hip/hip_runtime.h>
#include <math.h>

#define T_LEN 2048
#define NB 2
#define E_DIM 1024
#define F_DIM 1536
#define HQn 16
#define HKn 4
#define Dh 64
#define WIN 1024
#define GATE_CH 12
#define PS 72   // LDS row stride (elems): 144B, 16B-aligned

typedef unsigned short u16;
typedef unsigned int u32;
typedef __attribute__((ext_vector_type(8))) short bf16x8;
typedef __attribute__((ext_vector_type(4))) short bf16x4;
typedef __attribute__((ext_vector_type(4))) float f32x4;

// K=16 bf16 MFMA: probe builtin names; asm fallback (instr exists on gfx950).
#if __has_builtin(__builtin_amdgcn_mfma_f32_16x16x16bf16_1k)
#define MFMA16(A, B, C) __builtin_amdgcn_mfma_f32_16x16x16bf16_1k(A, B, C, 0, 0, 0)
#elif __has_builtin(__builtin_amdgcn_mfma_f32_16x16x16_bf16)
#define MFMA16(A, B, C) __builtin_amdgcn_mfma_f32_16x16x16_bf16(A, B, C, 0, 0, 0)
#else
static __device__ __forceinline__ f32x4 mfma16_asm(bf16x4 a, bf16x4 b, f32x4 c) {
  f32x4 d;
  asm volatile("s_nop 1\n\tv_mfma_f32_16x16x16_bf16 %0, %1, %2, %3\n\ts_nop 7\n\ts_nop 7"
               : "=v"(d) : "v"(a), "v"(b), "v"(c));
  return d;
}
#define MFMA16(A, B, C) mfma16_asm(A, B, C)
#endif

__device__ __forceinline__ u16 f2bf(float f) {
  union { float f; unsigned int u; } v; v.f = f;
  unsigned int u = v.u + 0x7FFF + ((v.u >> 16) & 1);
  return (u16)(u >> 16);
}
__device__ __forceinline__ float bf2f(u16 h) {
  union { unsigned int u; float f; } v; v.u = ((unsigned int)h) << 16;
  return v.f;
}
// pack two f32 -> two bf16 (round-half-up) in ONE v_perm + 2 adds
__device__ __forceinline__ u32 pack_bf2(float hi, float lo) {
  union { float f; u32 u; } a, b; a.f = hi; b.f = lo;
  return __builtin_amdgcn_perm(a.u + 0x8000u, b.u + 0x8000u, 0x07060302u);
}
__device__ __forceinline__ void async_copy16(const void* g, void* l) {
  __builtin_amdgcn_global_load_lds(
      (const __attribute__((address_space(1))) unsigned int*)g,
      (__attribute__((address_space(3))) unsigned int*)l, 16, 0, 0);
}

// ---------------------------------------------------------------------------
// fp32 -> bf16 (RNE) for x / wqkv / wo in ONE launch.
// ---------------------------------------------------------------------------
__global__ __launch_bounds__(256) void cvt_all(
    const float4* __restrict__ x, const float4* __restrict__ wqkv,
    const float4* __restrict__ wo, uint2* __restrict__ xb,
    uint2* __restrict__ wqb, uint2* __restrict__ wob)
{
  int blk = blockIdx.x;
  const float4* in; uint2* out; int i;
  if (blk < 4096)       { in = x;    out = xb;  i = blk * 256 + threadIdx.x; }
  else if (blk < 5632)  { in = wqkv; out = wqb; i = (blk - 4096) * 256 + threadIdx.x; }
  else                  { in = wo;   out = wob; i = (blk - 5632) * 256 + threadIdx.x; }
  float4 v = in[i];
  uint2 o;
  o.x = (unsigned)f2bf(v.x) | ((unsigned)f2bf(v.y) << 16);
  o.y = (unsigned)f2bf(v.z) | ((unsigned)f2bf(v.w) << 16);
  out[i] = o;
}

// ---------------------------------------------------------------------------
// bf16 MFMA GEMM, templated tile: C[M][N] = A[M][K] * B[N][K]^T
// 4 waves in 2x2; wave tile (BM/2)x(BN/2); 16x16x32 MFMAs. BK=32.
// Smaller tiles than m97's 128x128 on purpose: these GEMMs are small-K and
// latency-bound, so occupancy (blocks/CU) beats staging amortization.
// ---------------------------------------------------------------------------
template<int BM, int BN, int STORE_BF16>
__global__ __launch_bounds__(256) void gemm_bf16(
    const u16* __restrict__ A, const u16* __restrict__ B,
    void* __restrict__ Cv, int M, int N, int K)
{
  constexpr int MI = BM / 32, NJ = BN / 32;
  __shared__ u16 As[BM * 32];
  __shared__ u16 Bs[BN * 32];
  const int tid = threadIdx.x;
  const int wave = tid >> 6, lane = tid & 63;
  const int quad = lane >> 4, lanelow = lane & 15;
  const int row0 = blockIdx.x * BM;
  const int col0 = blockIdx.y * BN;
  const int wm = (wave >> 1) * (BM / 2), wn = (wave & 1) * (BN / 2);

  f32x4 acc[MI][NJ];
#pragma unroll
  for (int i = 0; i < MI; ++i)
#pragma unroll
    for (int j = 0; j < NJ; ++j) acc[i][j] = (f32x4){0.f, 0.f, 0.f, 0.f};

  const int r1 = wave * 16 + (lane >> 2);
  const int c1 = (lane & 3) * 8;

  for (int k0 = 0; k0 < K; k0 += 32) {
    __syncthreads();
#pragma unroll
    for (int p = 0; p < BM / 64; ++p)
      async_copy16(A + (size_t)(row0 + r1 + p * 64) * K + k0 + c1,
                   &As[(r1 + p * 64) * 32 + c1]);
#pragma unroll
    for (int p = 0; p < BN / 64; ++p)
      async_copy16(B + (size_t)(col0 + r1 + p * 64) * K + k0 + c1,
                   &Bs[(r1 + p * 64) * 32 + c1]);
    __syncthreads();

    bf16x8 a[MI], b[NJ];
#pragma unroll
    for (int i = 0; i < MI; ++i)
      a[i] = *(const bf16x8*)&As[(wm + i * 16 + lanelow) * 32 + quad * 8];
#pragma unroll
    for (int j = 0; j < NJ; ++j)
      b[j] = *(const bf16x8*)&Bs[(wn + j * 16 + lanelow) * 32 + quad * 8];
#pragma unroll
    for (int i = 0; i < MI; ++i)
#pragma unroll
      for (int j = 0; j < NJ; ++j)
        acc[i][j] = __builtin_amdgcn_mfma_f32_16x16x32_bf16(a[i], b[j], acc[i][j], 0, 0, 0);
  }

#pragma unroll
  for (int i = 0; i < MI; ++i)
#pragma unroll
    for (int j = 0; j < NJ; ++j) {
      int r = row0 + wm + i * 16 + quad * 4;
      int c = col0 + wn + j * 16 + lanelow;
#pragma unroll
      for (int reg = 0; reg < 4; ++reg) {
        if (STORE_BF16)
          ((u16*)Cv)[(size_t)(r + reg) * N + c] = f2bf(acc[i][j][reg]);
        else
          ((float*)Cv)[(size_t)(r + reg) * N + c] = acc[i][j][reg];
      }
    }
}

// ---------------------------------------------------------------------------
// postproc: gate = 3*sigmoid(x[:,:12]@wg^T); RoPE+RMS on q,k; v += gate*ve.
// ---------------------------------------------------------------------------
__global__ __launch_bounds__(256) void postproc_bf(
    const u16* __restrict__ qkv, const float* __restrict__ x,
    const float* __restrict__ ve, const float* __restrict__ rcos,
    const float* __restrict__ rsin, const float* __restrict__ wg,
    u16* __restrict__ qa, u16* __restrict__ ka, u16* __restrict__ va)
{
  const int token = blockIdx.x;
  const int t = token & (T_LEN - 1);
  const int tid = threadIdx.x;
  const int wave = tid >> 6, lane = tid & 63;
  __shared__ float gate[HKn];
  if (tid < HKn) {
    float g = 0.f;
#pragma unroll
    for (int c = 0; c < GATE_CH; ++c)
      g += x[(size_t)token * E_DIM + c] * wg[tid * GATE_CH + c];
    gate[tid] = 3.f / (1.f + __expf(-g));
  }
  __syncthreads();
  const int half = lane & 31;
  for (int vi = wave; vi < HQn + HKn; vi += 4) {
    const u16* p = qkv + (size_t)token * F_DIM + vi * Dh;
    float c = rcos[t * 32 + half], s = rsin[t * 32 + half];
    float x1 = bf2f(p[half]), x2 = bf2f(p[half + 32]);
    float y = (lane < 32) ? (x1 * c - x2 * s) : (x1 * s + x2 * c);
    float ss = y * y;
#pragma unroll
    for (int o = 32; o; o >>= 1) ss += __shfl_xor(ss, o, 64);
    float v = y * rsqrtf(ss * (1.f / Dh) + 1e-8f);
    if (vi < HQn)
      qa[((size_t)token * HQn + vi) * Dh + lane] = f2bf(v * 0.1803368801f); // 0.125*log2(e)
    else
      ka[((size_t)token * HKn + (vi - HQn)) * Dh + lane] = f2bf(v);
  }
  {
    float g = gate[tid >> 6];
    size_t vidx = (size_t)token * (HKn * Dh) + tid;
    va[vidx] = f2bf(bf2f(qkv[(size_t)token * F_DIM + (HQn + HKn) * Dh + tid]) + g * ve[vidx]);
  }
}

// ---------------------------------------------------------------------------
// V transpose: va[tok][hk][d] -> vt[(b*4+hk)*64 + d][t]
// ---------------------------------------------------------------------------
__global__ __launch_bounds__(256) void transpose_v(
    const u16* __restrict__ va, u16* __restrict__ vt)
{
  __shared__ u16 tile[64][PS];
  const int bhk = blockIdx.y;
  const int b = bhk >> 2, hk = bhk & 3;
  const int t0 = blockIdx.x * 64;
  const int tid = threadIdx.x;
#pragma unroll
  for (int p = 0; p < 2; ++p) {
    int s = tid + p * 256;
    int r = s >> 3, seg = s & 7;
    *(uint4*)&tile[r][seg * 8] =
        *(const uint4*)(va + ((size_t)(b * T_LEN + t0 + r) * HKn + hk) * Dh + seg * 8);
  }
  __syncthreads();
#pragma unroll
  for (int p = 0; p < 2; ++p) {
    int s = tid + p * 256;
    int d = s >> 3, seg = s & 7;
    u16 tmp[8];
#pragma unroll
    for (int e = 0; e < 8; ++e) tmp[e] = tile[seg * 8 + e][d];
    *(uint4*)(vt + ((size_t)bhk * Dh + d) * T_LEN + t0 + seg * 8) = *(uint4*)tmp;
  }
}

// ---------------------------------------------------------------------------
// MFMA flash attention v4: 64-row q-tiles for occupancy (grid 1024 = 4/CU,
// 16 waves/CU). S^T formulation (P stays in registers, B-layout of K=16 MFMA),
// fixed-shift softmax (|S|<=11.54), double-buffered K/V + register prefetch,
// one barrier per k-tile. P packed via v_perm (round-half-up).
// ---------------------------------------------------------------------------
__global__ __launch_bounds__(256) void attn_mfma(
    const u16* __restrict__ qa, const u16* __restrict__ ka,
    const u16* __restrict__ vt_g, u16* __restrict__ att)
{
  __shared__ u16 Ks[2][64 * PS];   // [buf][j][d]
  __shared__ u16 Vt[2][64 * PS];   // [buf][d][j]
  const int qt = blockIdx.x, h = blockIdx.y, b = blockIdx.z;
  const int hk = h >> 2;
  const int qb = qt * 64;
  const int tid = threadIdx.x;
  const int wave = tid >> 6, lane = tid & 63;
  const int quad = lane >> 4, lanelow = lane & 15;

  // Q fragments (B-operand: n=q=lanelow, k=d=quad*8+j) direct from global
  bf16x8 aQ[2];
#pragma unroll
  for (int kk = 0; kk < 2; ++kk)
    aQ[kk] = *(const bf16x8*)(qa +
        ((size_t)(b * T_LEN + qb + wave * 16 + lanelow) * HQn + h) * Dh +
        kk * 32 + quad * 8);

  f32x4 O[4];                      // O^T C-layout (col=q=lanelow, row=d_local)
  float l = 0.f;
#pragma unroll
  for (int dt = 0; dt < 4; ++dt) O[dt] = (f32x4){0.f, 0.f, 0.f, 0.f};

  const int kt0 = (qt >= 16) ? qt - 16 : 0;
  const int kt1 = qt;

  const int sr0 = tid >> 3,         sc0 = (tid & 7) * 8;
  const int sr1 = (tid + 256) >> 3, sc1 = ((tid + 256) & 7) * 8;
  const u16* kg = ka + (size_t)(b * T_LEN) * (HKn * Dh) + hk * Dh;
  const u16* vg = vt_g + (size_t)(b * HKn + hk) * Dh * T_LEN;

  { // prologue: stage tile kt0 into buf 0
    const int kb = kt0 * 64;
    uint4 k0 = *(const uint4*)(kg + (size_t)(kb + sr0) * (HKn * Dh) + sc0);
    uint4 k1 = *(const uint4*)(kg + (size_t)(kb + sr1) * (HKn * Dh) + sc1);
    uint4 v0 = *(const uint4*)(vg + (size_t)sr0 * T_LEN + kb + sc0);
    uint4 v1 = *(const uint4*)(vg + (size_t)sr1 * T_LEN + kb + sc1);
    *(uint4*)&Ks[0][sr0 * PS + sc0] = k0;
    *(uint4*)&Ks[0][sr1 * PS + sc1] = k1;
    *(uint4*)&Vt[0][sr0 * PS + sc0] = v0;
    *(uint4*)&Vt[0][sr1 * PS + sc1] = v1;
  }

  for (int kt = kt0; kt <= kt1; ++kt) {
    const int buf = (kt - kt0) & 1;
    const int kb = kt * 64;
    uint4 k0, k1, v0, v1;
    const bool more = (kt < kt1);
    if (more) {   // prefetch kt+1 (in flight during compute)
      const int nb = kb + 64;
      k0 = *(const uint4*)(kg + (size_t)(nb + sr0) * (HKn * Dh) + sc0);
      k1 = *(const uint4*)(kg + (size_t)(nb + sr1) * (HKn * Dh) + sc1);
      v0 = *(const uint4*)(vg + (size_t)sr0 * T_LEN + nb + sc0);
      v1 = *(const uint4*)(vg + (size_t)sr1 * T_LEN + nb + sc1);
    }
    __syncthreads();   // LDS[buf] writes from previous iter visible

    // S^T = K·Q^T: A = K-frag (m=j), B = Q-frag (n=q); -12 shift in C-init
    f32x4 St[4];
#pragma unroll
    for (int jt = 0; jt < 4; ++jt) {
      bf16x8 aK0 = *(const bf16x8*)&Ks[buf][(jt * 16 + lanelow) * PS + quad * 8];
      bf16x8 aK1 = *(const bf16x8*)&Ks[buf][(jt * 16 + lanelow) * PS + 32 + quad * 8];
      f32x4 acc = (f32x4){-12.f, -12.f, -12.f, -12.f};
      acc = __builtin_amdgcn_mfma_f32_16x16x32_bf16(aK0, aQ[0], acc, 0, 0, 0);
      acc = __builtin_amdgcn_mfma_f32_16x16x32_bf16(aK1, aQ[1], acc, 0, 0, 0);
      St[jt] = acc;
    }
    if (kt == kt1) {                 // diagonal tile: causal mask
#pragma unroll
      for (int jt = 0; jt < 4; ++jt)
#pragma unroll
        for (int rr = 0; rr < 4; ++rr) {
          int ig = qb + wave * 16 + lanelow;
          int jg = kb + jt * 16 + quad * 4 + rr;
          if (jg > ig) St[jt][rr] = -1e30f;
        }
    } else if (kt == kt0 && qt >= 16) {   // trailing tile: window mask
#pragma unroll
      for (int jt = 0; jt < 4; ++jt)
#pragma unroll
        for (int rr = 0; rr < 4; ++rr) {
          int ig = qb + wave * 16 + lanelow;
          int jg = kb + jt * 16 + quad * 4 + rr;
          if (jg < ig - WIN) St[jt][rr] = -1e30f;
        }
    }
    // P = exp2(S^T); lane-local l partial; pack 2 floats/instr via v_perm
    bf16x4 Pt[4];
#pragma unroll
    for (int jt = 0; jt < 4; ++jt) {
      float p0 = __builtin_amdgcn_exp2f(St[jt][0]);
      float p1 = __builtin_amdgcn_exp2f(St[jt][1]);
      float p2 = __builtin_amdgcn_exp2f(St[jt][2]);
      float p3 = __builtin_amdgcn_exp2f(St[jt][3]);
      l += (p0 + p1) + (p2 + p3);
      union { uint2 u; bf16x4 v; } pu;
      pu.u.x = pack_bf2(p1, p0);
      pu.u.y = pack_bf2(p3, p2);
      Pt[jt] = pu.v;
    }
    // PV: O^T[d][q] += V^T-frag (A: m=d, k=j) * P^T (B straight from regs)
#pragma unroll
    for (int dt = 0; dt < 4; ++dt)
#pragma unroll
      for (int jt = 0; jt < 4; ++jt) {
        bf16x4 aV = *(const bf16x4*)&Vt[buf][(dt * 16 + lanelow) * PS + jt * 16 + quad * 4];
        O[dt] = MFMA16(aV, Pt[jt], O[dt]);
      }
    if (more) {   // write prefetched tile into the other buffer
      const int nbuf = buf ^ 1;
      *(uint4*)&Ks[nbuf][sr0 * PS + sc0] = k0;
      *(uint4*)&Ks[nbuf][sr1 * PS + sc1] = k1;
      *(uint4*)&Vt[nbuf][sr0 * PS + sc0] = v0;
      *(uint4*)&Vt[nbuf][sr1 * PS + sc1] = v1;
    }
  }

  // epilogue: reduce l across quads (q=lanelow fixed per lane), store O^T/l
  {
    float s = l;
    s += __shfl_xor(s, 16, 64);
    s += __shfl_xor(s, 32, 64);
    float inv = 1.f / s;
    int qg = qb + wave * 16 + lanelow;
    u16* obase = att + (size_t)(b * T_LEN + qg) * E_DIM + h * Dh;
#pragma unroll
    for (int dt = 0; dt < 4; ++dt) {
      bf16x4 ov;
      ov[0] = (short)f2bf(O[dt][0] * inv);
      ov[1] = (short)f2bf(O[dt][1] * inv);
      ov[2] = (short)f2bf(O[dt][2] * inv);
      ov[3] = (short)f2bf(O[dt][3] * inv);
      *(bf16x4*)(obase + dt * 16 + quad * 4) = ov;   // 8B store, d consecutive
    }
  }
}

// ---------------------------------------------------------------------------
extern "C" void kernel_launch(void* const* d_in, const int* in_sizes, int n_in,
                              void* d_out, int out_size, void* d_ws, size_t ws_size,
                              hipStream_t stream)
{
  const float* x    = (const float*)d_in[0];
  const float* ve   = (const float*)d_in[1];
  const float* rc   = (const float*)d_in[2];
  const float* rs   = (const float*)d_in[3];
  const float* wqkv = (const float*)d_in[4];
  const float* wg   = (const float*)d_in[5];
  const float* wo   = (const float*)d_in[6];
  float* out = (float*)d_out;

  char* ws = (char*)d_ws;
  u16* x_bf    = (u16*)(ws);                       //  8 MB  4096x1024
  u16* v_t     = x_bf;                             //  2 MB  (reuse, x_bf dead after gemm1)
  u16* wqkv_bf = (u16*)(ws + 8388608);             //  3 MB  1536x1024
  u16* wo_bf   = (u16*)(ws + 11534336);            //  2 MB  1024x1024
  u16* qkv_bf  = (u16*)(ws + 13631488);            // 12 MB  4096x1536
  u16* att     = qkv_bf;                           //  8 MB  (reuse, dead after postproc)
  u16* q_att   = (u16*)(ws + 26214400);            //  8 MB  4096x16x64
  u16* k_att   = (u16*)(ws + 34603008);            //  2 MB  4096x4x64
  u16* v_att   = (u16*)(ws + 36700160);            //  2 MB  4096x4x64

  cvt_all<<<6656, 256, 0, stream>>>((const float4*)x, (const float4*)wqkv,
                                    (const float4*)wo, (uint2*)x_bf,
                                    (uint2*)wqkv_bf, (uint2*)wo_bf);
  gemm_bf16<128, 64, 1><<<dim3(32, 24), 256, 0, stream>>>(x_bf, wqkv_bf, qkv_bf, 4096, F_DIM, E_DIM);
  postproc_bf<<<NB * T_LEN, 256, 0, stream>>>(qkv_bf, x, ve, rc, rs, wg, q_att, k_att, v_att);
  transpose_v<<<dim3(32, 8), 256, 0, stream>>>(v_att, v_t);
  attn_mfma<<<dim3(T_LEN / 64, HQn, NB), 256, 0, stream>>>(q_att, k_att, v_t, att);
  gemm_bf16<64, 64, 0><<<dim3(64, 16), 256, 0, stream>>>(att, wo_bf, out, 4096, E_DIM, E_DIM);
}